// Round 4
// baseline (560.078 us; speedup 1.0000x reference)
//
#include <hip/hip_runtime.h>
#include <hip/hip_bf16.h>
#include <stdint.h>

#define NN 100000
#define NE 1600000
#define FIN 100
#define HID 128
#define CLS 47
#define NBUK 391            // ceil(NN/256) buckets of 256 nodes

typedef __attribute__((ext_vector_type(8))) short bf16x8;
typedef __attribute__((ext_vector_type(4))) float f32x4;

#define AS1(p) ((const __attribute__((address_space(1))) void*)(p))
#define AS3(p) ((__attribute__((address_space(3))) void*)(p))

__device__ __forceinline__ uint16_t f2bf(float f) {
  union { float f; uint32_t u; } v; v.f = f;
  uint32_t r = v.u + 0x7fffu + ((v.u >> 16) & 1u);
  return (uint16_t)(r >> 16);
}

// ---- weight packing: B_l[j][k] (128 x 256) bf16; k<128 -> W_rel, k>=128 -> W_root (layer1 zero-padded)
// Plain row-major (no swizzle): gemm reads B directly from L2, no LDS.
__global__ void pack_weights(const float* __restrict__ W1r, const float* __restrict__ W1o,
                             const float* __restrict__ W2r, const float* __restrict__ W2o,
                             const float* __restrict__ W3r, const float* __restrict__ W3o,
                             uint16_t* __restrict__ B1, uint16_t* __restrict__ B2, uint16_t* __restrict__ B3) {
  int idx = blockIdx.x * 256 + threadIdx.x;      // < 3*128*256
  int l = idx >> 15;
  int rem = idx & 32767;
  int j = rem >> 8;
  int k = rem & 255;
  if (l == 0) {
    uint16_t v = 0;
    if (k < FIN) v = f2bf(W1r[j*FIN + k]);
    else if (k >= 128 && k < 128 + FIN) v = f2bf(W1o[j*FIN + (k - 128)]);
    B1[j*256 + k] = v;
  } else if (l == 1) {
    B2[j*256 + k] = (k < 128) ? f2bf(W2r[j*128 + k]) : f2bf(W2o[j*128 + (k - 128)]);
  } else {
    B3[j*256 + k] = (k < 128) ? f2bf(W3r[j*128 + k]) : f2bf(W3o[j*128 + (k - 128)]);
  }
}

// ---- W_lin [47,384] f32 -> Wlb [48,384] bf16 (row 47 zero)
__global__ void pack_wl(const float* __restrict__ Wl, uint16_t* __restrict__ Wlb) {
  int idx = blockIdx.x * 256 + threadIdx.x;      // < 48*384
  int r = idx / 384;
  int c = idx - r * 384;
  Wlb[idx] = (r < CLS) ? f2bf(Wl[r*384 + c]) : (uint16_t)0;
}

// ---- pad+convert x0 [N,100] f32 -> x0p [N,128] bf16 (zeros in cols 100..127); 4 nodes/block
__global__ __launch_bounds__(256) void pad_x0(const float* __restrict__ x0, uint16_t* __restrict__ x0p) {
  int n = blockIdx.x * 4 + (threadIdx.x >> 6);
  int c = 2 * (threadIdx.x & 63);
  uint32_t o = 0;
  if (c < FIN) {
    float2 v = *(const float2*)(x0 + (size_t)n*FIN + c);
    o = ((uint32_t)f2bf(v.y) << 16) | (uint32_t)f2bf(v.x);
  }
  *(uint32_t*)(x0p + (size_t)n*HID + c) = o;
}

// ======== binned CSR build (write-coalescing-aware) ========
// Stage 1: per-bucket counts via LDS pre-aggregation (196 blocks x 8192-edge tiles)
__global__ __launch_bounds__(512) void bucket_hist(const int* __restrict__ dst, int* __restrict__ bcnt) {
  __shared__ int h[NBUK];
  int tid = threadIdx.x;
  for (int i = tid; i < NBUK; i += 512) h[i] = 0;
  __syncthreads();
  int tile0 = blockIdx.x * 8192;
  int n = NE - tile0; if (n > 8192) n = 8192;
  for (int i = tid; i < n; i += 512) atomicAdd(&h[dst[tile0 + i] >> 8], 1);
  __syncthreads();
  for (int i = tid; i < NBUK; i += 512) if (h[i]) atomicAdd(&bcnt[i], h[i]);
}

// Stage 2: exclusive scan of 391 bucket counts -> bases (fill = working copy)
__global__ __launch_bounds__(512) void bucket_scan(const int* __restrict__ bcnt,
                                                   int* __restrict__ bfill, int* __restrict__ bbase) {
  __shared__ int sh[512];
  int t = threadIdx.x;
  int v = (t < NBUK) ? bcnt[t] : 0;
  sh[t] = v;
  __syncthreads();
  for (int off = 1; off < 512; off <<= 1) {
    int tv = (t >= off) ? sh[t - off] : 0;
    __syncthreads();
    sh[t] += tv;
    __syncthreads();
  }
  if (t < NBUK) {
    int e = sh[t] - v;
    bfill[t] = e;
    bbase[t] = e;
  }
  if (t == 0) bbase[NBUK] = NE;
}

// Stage 3: binned scatter. Each block claims contiguous per-bucket chunks so all
// writes to a chunk come from ONE CU -> L2 write-combining -> full-line writebacks.
// Packed rec: x = src | dstLocal<<17 (src<2^17, dstLocal<256), y = weight bits.
__global__ __launch_bounds__(512) void binscat(const int* __restrict__ src, const int* __restrict__ dst,
                                               const float* __restrict__ ew,
                                               int* __restrict__ bfill, int2* __restrict__ ebin) {
  __shared__ int h[NBUK];
  __shared__ int base[NBUK];
  int tid = threadIdx.x;
  for (int i = tid; i < NBUK; i += 512) h[i] = 0;
  __syncthreads();
  int tile0 = blockIdx.x * 8192;
  int n = NE - tile0; if (n > 8192) n = 8192;
  for (int i = tid; i < n; i += 512) atomicAdd(&h[dst[tile0 + i] >> 8], 1);
  __syncthreads();
  for (int i = tid; i < NBUK; i += 512) base[i] = h[i] ? atomicAdd(&bfill[i], h[i]) : 0;
  __syncthreads();
  for (int i = tid; i < NBUK; i += 512) h[i] = 0;
  __syncthreads();
  for (int i = tid; i < n; i += 512) {
    int e = tile0 + i;
    int d = dst[e];
    int b = d >> 8;
    int r = atomicAdd(&h[b], 1);
    ebin[base[b] + r] = make_int2(src[e] | ((d & 255) << 17), __float_as_int(ew[e]));
  }
}

// Stage 4: one block per bucket. LDS hist+scan over the 256 local nodes gives
// row_start directly, then scatters the final erec {src byte-offset, weight}
// within this bucket's ~33KB window — single CU => coalesced writebacks.
__global__ __launch_bounds__(256) void bucket_csr(const int2* __restrict__ ebin,
                                                  const int* __restrict__ bbase,
                                                  int* __restrict__ row_start,
                                                  int2* __restrict__ erec) {
  __shared__ int sh[256];
  __shared__ int fill[256];
  int b = blockIdx.x;
  int tid = threadIdx.x;
  int ebase = bbase[b], eend = bbase[b + 1];
  int cnt = eend - ebase;
  sh[tid] = 0;
  __syncthreads();
  for (int i = tid; i < cnt; i += 256) atomicAdd(&sh[(uint32_t)ebin[ebase + i].x >> 17], 1);
  __syncthreads();
  int histv = sh[tid];
  __syncthreads();
  for (int off = 1; off < 256; off <<= 1) {
    int tv = (tid >= off) ? sh[tid - off] : 0;
    __syncthreads();
    sh[tid] += tv;
    __syncthreads();
  }
  int excl = sh[tid] - histv;
  int node = b * 256 + tid;
  if (node <= NN) row_start[node] = ebase + excl;   // node==NN -> ebase+cnt == NE
  fill[tid] = ebase + excl;
  __syncthreads();
  for (int i = tid; i < cnt; i += 256) {
    int2 rec = ebin[ebase + i];
    int dl = (uint32_t)rec.x >> 17;
    int s = rec.x & 0x1FFFF;
    int pos = atomicAdd(&fill[dl], 1);
    erec[pos] = make_int2(s << 8, rec.y);           // s*256 = byte offset (HID*2 per row)
  }
}

// ---- SpMM: agg[n,:] = sum_{e in row n} w_e * x[src_e,:]
// Four nodes per wave: each 16-lane quarter owns its OWN row + edge stream.
// Lane covers 8 cols (16B); 16 lanes span the 128-col row; batches of 8 edges
// -> 8KB of gathers in flight per wave, 256B contiguous store per quarter.
__global__ __launch_bounds__(256) void spmm_kernel(const uint16_t* __restrict__ x,
                                                   const int* __restrict__ row_start,
                                                   const int2* __restrict__ erec,
                                                   uint16_t* __restrict__ agg) {
  int wave = threadIdx.x >> 6;
  int l = threadIdx.x & 63;
  int q = l >> 4, li = l & 15;
  int n = blockIdx.x * 16 + wave * 4 + q;
  int s0 = row_start[n], s1 = row_start[n + 1];
  const char* xb = (const char*)x;
  int loff = 16 * li;
  float a[8];
  #pragma unroll
  for (int v = 0; v < 8; ++v) a[v] = 0.f;
  const int2* ep = erec + s0;
  for (int e0 = s0; e0 < s1; e0 += 8, ep += 8) {
    int2 r[8];
    #pragma unroll
    for (int u = 0; u < 8; ++u) r[u] = ep[u];      // imm-offset loads off one base
    uint4 pair[8];
    #pragma unroll
    for (int u = 0; u < 8; ++u)
      pair[u] = *(const uint4*)(xb + (size_t)(uint32_t)(r[u].x + loff));
    #pragma unroll
    for (int u = 0; u < 8; ++u) {
      float w = (e0 + u < s1) ? __int_as_float(r[u].y) : 0.f;
      uint32_t wd[4] = {pair[u].x, pair[u].y, pair[u].z, pair[u].w};
      #pragma unroll
      for (int v = 0; v < 4; ++v) {
        union { uint32_t u32; float f; } lo, hi;
        lo.u32 = wd[v] << 16; hi.u32 = wd[v] & 0xffff0000u;
        a[2*v]   += w * lo.f;
        a[2*v+1] += w * hi.f;
      }
    }
  }
  uint4 o;
  o.x = ((uint32_t)f2bf(a[1]) << 16) | (uint32_t)f2bf(a[0]);
  o.y = ((uint32_t)f2bf(a[3]) << 16) | (uint32_t)f2bf(a[2]);
  o.z = ((uint32_t)f2bf(a[5]) << 16) | (uint32_t)f2bf(a[4]);
  o.w = ((uint32_t)f2bf(a[7]) << 16) | (uint32_t)f2bf(a[6]);
  *(uint4*)(agg + (size_t)n*HID + 8*li) = o;
}

// ---- fused GEMM: out = relu([A1|A2] @ B^T + bias)
// Block tile: 64 rows x 128 cols, 4 waves as 2(M)x2(N). NO LDS, NO barriers:
// B (64KB) stays L2-resident; A and B fragments read straight from global.
__global__ __launch_bounds__(256) void gemm_kernel(const uint16_t* __restrict__ A1, const uint16_t* __restrict__ A2,
                                                   const uint16_t* __restrict__ Bm, const float* __restrict__ bias,
                                                   uint16_t* __restrict__ out) {
  int t = threadIdx.x;
  int n0 = blockIdx.x * 64;
  int lane = t & 63, wave = t >> 6;
  int l15 = lane & 15, quad = lane >> 4;
  int wm = (wave >> 1) * 32;             // 0 or 32
  int wn = (wave & 1) * 64;              // 0 or 64

  uint32_t rowoff[2];
  #pragma unroll
  for (int mi = 0; mi < 2; ++mi) {
    int rowA = n0 + wm + mi * 16 + l15;
    if (rowA >= NN) rowA = NN - 1;
    rowoff[mi] = (uint32_t)rowA * HID;
  }

  f32x4 acc[2][4];
  #pragma unroll
  for (int i = 0; i < 2; ++i)
    #pragma unroll
    for (int j = 0; j < 4; ++j) acc[i][j] = (f32x4){0.f, 0.f, 0.f, 0.f};

  #pragma unroll
  for (int kt = 0; kt < 8; ++kt) {
    const uint16_t* Asrc = (kt < 4) ? A1 : A2;
    int klocal = (kt & 3) * 32 + quad * 8;
    bf16x8 af[2];
    #pragma unroll
    for (int mi = 0; mi < 2; ++mi)
      af[mi] = *(const bf16x8*)(Asrc + (size_t)rowoff[mi] + klocal);
    int kel = kt * 32 + quad * 8;        // <= 248
    bf16x8 bfr[4];
    #pragma unroll
    for (int ni = 0; ni < 4; ++ni) {
      int j = wn + ni * 16 + l15;        // < 128
      bfr[ni] = *(const bf16x8*)(Bm + j * 256 + kel);
    }
    #pragma unroll
    for (int mi = 0; mi < 2; ++mi)
      #pragma unroll
      for (int ni = 0; ni < 4; ++ni)
        acc[mi][ni] = __builtin_amdgcn_mfma_f32_16x16x32_bf16(af[mi], bfr[ni], acc[mi][ni], 0, 0, 0);
  }

  #pragma unroll
  for (int mi = 0; mi < 2; ++mi) {
    #pragma unroll
    for (int ni = 0; ni < 4; ++ni) {
      int c = wn + ni * 16 + l15;        // < 128
      float bc = bias[c];
      #pragma unroll
      for (int i = 0; i < 4; ++i) {
        int r = n0 + wm + mi * 16 + quad * 4 + i;
        if (r < NN) {
          float v = acc[mi][ni][i] + bc;
          v = v > 0.f ? v : 0.f;
          out[(size_t)r*HID + c] = f2bf(v);
        }
      }
    }
  }
}

// ---- final: logits = [x1|x2|x3] @ Wlb^T + bl ; log_softmax ; store f32
__global__ __launch_bounds__(256) void final_kernel(const uint16_t* __restrict__ x1, const uint16_t* __restrict__ x2,
                                                    const uint16_t* __restrict__ x3,
                                                    const uint16_t* __restrict__ Wlb, const float* __restrict__ bl,
                                                    float* __restrict__ out) {
  int t = threadIdx.x;
  int lane = t & 63, wave = t >> 6;
  int n0 = blockIdx.x * 64 + wave * 16;
  int l15 = lane & 15, quad = lane >> 4;

  f32x4 acc[3];
  #pragma unroll
  for (int i = 0; i < 3; ++i) acc[i] = (f32x4){0.f, 0.f, 0.f, 0.f};

  int arow = n0 + l15; if (arow >= NN) arow = NN - 1;

  #pragma unroll
  for (int kt = 0; kt < 12; ++kt) {
    const uint16_t* xs = (kt < 4) ? x1 : (kt < 8) ? x2 : x3;
    int klocal = (kt & 3) * 32 + quad * 8;
    bf16x8 af = *(const bf16x8*)(xs + (size_t)arow*HID + klocal);
    int kglob = kt * 32 + quad * 8;
    #pragma unroll
    for (int nt = 0; nt < 3; ++nt) {
      int c = nt*16 + l15;                 // < 48, row 47 of Wlb is zero
      bf16x8 bfr = *(const bf16x8*)(Wlb + (size_t)c*(3*HID) + kglob);
      acc[nt] = __builtin_amdgcn_mfma_f32_16x16x32_bf16(af, bfr, acc[nt], 0, 0, 0);
    }
  }

  float bias[3]; bool valid[3];
  #pragma unroll
  for (int nt = 0; nt < 3; ++nt) {
    int c = nt*16 + l15;
    valid[nt] = (c < CLS);
    bias[nt] = valid[nt] ? bl[c] : 0.f;
  }

  #pragma unroll
  for (int i = 0; i < 4; ++i) {
    int r = n0 + quad*4 + i;
    float v0 = acc[0][i] + bias[0];
    float v1 = acc[1][i] + bias[1];
    float v2 = valid[2] ? (acc[2][i] + bias[2]) : -INFINITY;
    float m = fmaxf(v0, fmaxf(v1, v2));
    #pragma unroll
    for (int off = 8; off >= 1; off >>= 1) m = fmaxf(m, __shfl_xor(m, off, 64));
    float s = __expf(v0 - m) + __expf(v1 - m) + (valid[2] ? __expf(v2 - m) : 0.f);
    #pragma unroll
    for (int off = 8; off >= 1; off >>= 1) s += __shfl_xor(s, off, 64);
    float lse = m + __logf(s);
    if (r < NN) {
      out[(size_t)r*CLS + l15]      = v0 - lse;
      out[(size_t)r*CLS + 16 + l15] = v1 - lse;
      if (valid[2]) out[(size_t)r*CLS + 32 + l15] = v2 - lse;
    }
  }
}

extern "C" void kernel_launch(void* const* d_in, const int* in_sizes, int n_in,
                              void* d_out, int out_size, void* d_ws, size_t ws_size,
                              hipStream_t stream) {
  (void)in_sizes; (void)n_in; (void)out_size; (void)ws_size;
  const float* x0  = (const float*)d_in[0];
  const int*   ei  = (const int*)d_in[1];
  const float* ew  = (const float*)d_in[2];
  const float* W1r = (const float*)d_in[3];
  const float* W1o = (const float*)d_in[4];
  const float* b1  = (const float*)d_in[5];
  const float* W2r = (const float*)d_in[6];
  const float* W2o = (const float*)d_in[7];
  const float* b2  = (const float*)d_in[8];
  const float* W3r = (const float*)d_in[9];
  const float* W3o = (const float*)d_in[10];
  const float* b3  = (const float*)d_in[11];
  const float* Wl  = (const float*)d_in[12];
  const float* bl  = (const float*)d_in[13];
  const int* src = ei;
  const int* dst = ei + NE;

  char* ws = (char*)d_ws;
  size_t off = 0;
  auto alloc = [&](size_t bytes) -> void* {
    void* p = ws + off;
    off += (bytes + 255) & ~(size_t)255;
    return p;
  };
  uint16_t* x0p = (uint16_t*)alloc((size_t)NN * HID * 2);   // also reused as xb2
  uint16_t* xb1 = (uint16_t*)alloc((size_t)NN * HID * 2);
  uint16_t* xb3 = (uint16_t*)alloc((size_t)NN * HID * 2);
  uint16_t* agg = (uint16_t*)alloc((size_t)NN * HID * 2);
  int2*   erec      = (int2*)alloc((size_t)(NE + 16) * 8);  // +16 zero-weight pad recs
  int2*   ebin      = (int2*)alloc((size_t)NE * 8);
  int*    row_start = (int*)alloc((size_t)(NN + 1) * 4);
  int*    bcnt      = (int*)alloc(NBUK * 4);
  int*    bfill     = (int*)alloc(NBUK * 4);
  int*    bbase     = (int*)alloc((NBUK + 1) * 4);
  uint16_t* B1 = (uint16_t*)alloc(128 * 256 * 2);
  uint16_t* B2 = (uint16_t*)alloc(128 * 256 * 2);
  uint16_t* B3 = (uint16_t*)alloc(128 * 256 * 2);
  uint16_t* Wlb = (uint16_t*)alloc(48 * 384 * 2);
  uint16_t* xb2 = x0p;   // alias: x0p dead after layer-1 GEMM

  const int TB = (NE + 8191) / 8192;      // 196 tiles

  hipMemsetAsync(bcnt, 0, NBUK * 4, stream);
  hipMemsetAsync(erec + NE, 0, 16 * sizeof(int2), stream);  // pad: w=0, offset 0
  pack_weights<<<384, 256, 0, stream>>>(W1r, W1o, W2r, W2o, W3r, W3o, B1, B2, B3);
  pack_wl<<<72, 256, 0, stream>>>(Wl, Wlb);
  pad_x0<<<NN / 4, 256, 0, stream>>>(x0, x0p);
  bucket_hist<<<TB, 512, 0, stream>>>(dst, bcnt);
  bucket_scan<<<1, 512, 0, stream>>>(bcnt, bfill, bbase);
  binscat<<<TB, 512, 0, stream>>>(src, dst, ew, bfill, ebin);
  bucket_csr<<<NBUK, 256, 0, stream>>>(ebin, bbase, row_start, erec);

  spmm_kernel<<<NN / 16, 256, 0, stream>>>(x0p, row_start, erec, agg);
  gemm_kernel<<<(NN + 63) / 64, 256, 0, stream>>>(agg, x0p, B1, b1, xb1);
  spmm_kernel<<<NN / 16, 256, 0, stream>>>(xb1, row_start, erec, agg);
  gemm_kernel<<<(NN + 63) / 64, 256, 0, stream>>>(agg, xb1, B2, b2, xb2);
  spmm_kernel<<<NN / 16, 256, 0, stream>>>(xb2, row_start, erec, agg);
  gemm_kernel<<<(NN + 63) / 64, 256, 0, stream>>>(agg, xb2, B3, b3, xb3);

  final_kernel<<<(NN + 63) / 64, 256, 0, stream>>>(xb1, xb2, xb3, Wlb, bl, (float*)d_out);
}

// Round 5
// 524.474 us; speedup vs baseline: 1.0679x; 1.0679x over previous
//
#include <hip/hip_runtime.h>
#include <hip/hip_bf16.h>
#include <stdint.h>

#define NN 100000
#define NE 1600000
#define FIN 100
#define HID 128
#define CLS 47
#define NBUK 391            // ceil(NN/256) buckets of 256 nodes

typedef __attribute__((ext_vector_type(8))) short bf16x8;
typedef __attribute__((ext_vector_type(4))) float f32x4;

#define AS1(p) ((const __attribute__((address_space(1))) void*)(p))
#define AS3(p) ((__attribute__((address_space(3))) void*)(p))

__device__ __forceinline__ uint16_t f2bf(float f) {
  union { float f; uint32_t u; } v; v.f = f;
  uint32_t r = v.u + 0x7fffu + ((v.u >> 16) & 1u);
  return (uint16_t)(r >> 16);
}

// ---- weight packing: B_l[j][k] (128 x 256) bf16; k<128 -> W_rel, k>=128 -> W_root (layer1 zero-padded)
__global__ void pack_weights(const float* __restrict__ W1r, const float* __restrict__ W1o,
                             const float* __restrict__ W2r, const float* __restrict__ W2o,
                             const float* __restrict__ W3r, const float* __restrict__ W3o,
                             uint16_t* __restrict__ B1, uint16_t* __restrict__ B2, uint16_t* __restrict__ B3) {
  int idx = blockIdx.x * 256 + threadIdx.x;      // < 3*128*256
  int l = idx >> 15;
  int rem = idx & 32767;
  int j = rem >> 8;
  int k = rem & 255;
  if (l == 0) {
    uint16_t v = 0;
    if (k < FIN) v = f2bf(W1r[j*FIN + k]);
    else if (k >= 128 && k < 128 + FIN) v = f2bf(W1o[j*FIN + (k - 128)]);
    B1[j*256 + k] = v;
  } else if (l == 1) {
    B2[j*256 + k] = (k < 128) ? f2bf(W2r[j*128 + k]) : f2bf(W2o[j*128 + (k - 128)]);
  } else {
    B3[j*256 + k] = (k < 128) ? f2bf(W3r[j*128 + k]) : f2bf(W3o[j*128 + (k - 128)]);
  }
}

// ---- W_lin [47,384] f32 -> Wlb [48,384] bf16 (row 47 zero)
__global__ void pack_wl(const float* __restrict__ Wl, uint16_t* __restrict__ Wlb) {
  int idx = blockIdx.x * 256 + threadIdx.x;      // < 48*384
  int r = idx / 384;
  int c = idx - r * 384;
  Wlb[idx] = (r < CLS) ? f2bf(Wl[r*384 + c]) : (uint16_t)0;
}

// ---- pad+convert x0 [N,100] f32 -> x0p [N,128] bf16 (zeros in cols 100..127); 4 nodes/block
__global__ __launch_bounds__(256) void pad_x0(const float* __restrict__ x0, uint16_t* __restrict__ x0p) {
  int n = blockIdx.x * 4 + (threadIdx.x >> 6);
  int c = 2 * (threadIdx.x & 63);
  uint32_t o = 0;
  if (c < FIN) {
    float2 v = *(const float2*)(x0 + (size_t)n*FIN + c);
    o = ((uint32_t)f2bf(v.y) << 16) | (uint32_t)f2bf(v.x);
  }
  *(uint32_t*)(x0p + (size_t)n*HID + c) = o;
}

// ======== binned CSR build (write-coalescing-aware) ========
// Stage 1: per-bucket counts via LDS pre-aggregation (196 blocks x 8192-edge tiles)
__global__ __launch_bounds__(512) void bucket_hist(const int* __restrict__ dst, int* __restrict__ bcnt) {
  __shared__ int h[NBUK];
  int tid = threadIdx.x;
  for (int i = tid; i < NBUK; i += 512) h[i] = 0;
  __syncthreads();
  int tile0 = blockIdx.x * 8192;
  int n = NE - tile0; if (n > 8192) n = 8192;
  for (int i = tid; i < n; i += 512) atomicAdd(&h[dst[tile0 + i] >> 8], 1);
  __syncthreads();
  for (int i = tid; i < NBUK; i += 512) if (h[i]) atomicAdd(&bcnt[i], h[i]);
}

// Stage 2: exclusive scan of 391 bucket counts -> bases (fill = working copy)
__global__ __launch_bounds__(512) void bucket_scan(const int* __restrict__ bcnt,
                                                   int* __restrict__ bfill, int* __restrict__ bbase) {
  __shared__ int sh[512];
  int t = threadIdx.x;
  int v = (t < NBUK) ? bcnt[t] : 0;
  sh[t] = v;
  __syncthreads();
  for (int off = 1; off < 512; off <<= 1) {
    int tv = (t >= off) ? sh[t - off] : 0;
    __syncthreads();
    sh[t] += tv;
    __syncthreads();
  }
  if (t < NBUK) {
    int e = sh[t] - v;
    bfill[t] = e;
    bbase[t] = e;
  }
  if (t == 0) bbase[NBUK] = NE;
}

// Stage 3: binned scatter. Each block claims contiguous per-bucket chunks so all
// writes to a chunk come from ONE CU -> L2 write-combining -> full-line writebacks.
// Packed rec: x = src | dstLocal<<17 (src<2^17, dstLocal<256), y = weight bits.
__global__ __launch_bounds__(512) void binscat(const int* __restrict__ src, const int* __restrict__ dst,
                                               const float* __restrict__ ew,
                                               int* __restrict__ bfill, int2* __restrict__ ebin) {
  __shared__ int h[NBUK];
  __shared__ int base[NBUK];
  int tid = threadIdx.x;
  for (int i = tid; i < NBUK; i += 512) h[i] = 0;
  __syncthreads();
  int tile0 = blockIdx.x * 8192;
  int n = NE - tile0; if (n > 8192) n = 8192;
  for (int i = tid; i < n; i += 512) atomicAdd(&h[dst[tile0 + i] >> 8], 1);
  __syncthreads();
  for (int i = tid; i < NBUK; i += 512) base[i] = h[i] ? atomicAdd(&bfill[i], h[i]) : 0;
  __syncthreads();
  for (int i = tid; i < NBUK; i += 512) h[i] = 0;
  __syncthreads();
  for (int i = tid; i < n; i += 512) {
    int e = tile0 + i;
    int d = dst[e];
    int b = d >> 8;
    int r = atomicAdd(&h[b], 1);
    ebin[base[b] + r] = make_int2(src[e] | ((d & 255) << 17), __float_as_int(ew[e]));
  }
}

// Stage 4: one block per bucket. LDS hist+scan over the 256 local nodes gives
// row_start directly, then scatters the final erec {src byte-offset, weight}
// within this bucket's ~33KB window — single CU => coalesced writebacks.
__global__ __launch_bounds__(256) void bucket_csr(const int2* __restrict__ ebin,
                                                  const int* __restrict__ bbase,
                                                  int* __restrict__ row_start,
                                                  int2* __restrict__ erec) {
  __shared__ int sh[256];
  __shared__ int fill[256];
  int b = blockIdx.x;
  int tid = threadIdx.x;
  int ebase = bbase[b], eend = bbase[b + 1];
  int cnt = eend - ebase;
  sh[tid] = 0;
  __syncthreads();
  for (int i = tid; i < cnt; i += 256) atomicAdd(&sh[(uint32_t)ebin[ebase + i].x >> 17], 1);
  __syncthreads();
  int histv = sh[tid];
  __syncthreads();
  for (int off = 1; off < 256; off <<= 1) {
    int tv = (tid >= off) ? sh[tid - off] : 0;
    __syncthreads();
    sh[tid] += tv;
    __syncthreads();
  }
  int excl = sh[tid] - histv;
  int node = b * 256 + tid;
  if (node <= NN) row_start[node] = ebase + excl;   // node==NN -> ebase+cnt == NE
  fill[tid] = ebase + excl;
  __syncthreads();
  for (int i = tid; i < cnt; i += 256) {
    int2 rec = ebin[ebase + i];
    int dl = (uint32_t)rec.x >> 17;
    int s = rec.x & 0x1FFFF;
    int pos = atomicAdd(&fill[dl], 1);
    erec[pos] = make_int2(s << 8, rec.y);           // s*256 = byte offset (HID*2 per row)
  }
}

// ---- SpMM: agg[n,:] = sum_{e in row n} w_e * x[src_e,:]
// Two nodes per wave: each 32-lane half owns its OWN row and edge stream.
// Lane covers 4 cols (8B); batches of 8 edges -> 16 gathers in flight per wave,
// no cross-half reduction, 512B contiguous store per wave. (R3-measured: 61.4us)
__global__ __launch_bounds__(256) void spmm_kernel(const uint16_t* __restrict__ x,
                                                   const int* __restrict__ row_start,
                                                   const int2* __restrict__ erec,
                                                   uint16_t* __restrict__ agg) {
  int wave = threadIdx.x >> 6;
  int l = threadIdx.x & 63;
  int half = l >> 5, li = l & 31;
  int n = blockIdx.x * 8 + wave * 2 + half;
  int s0 = row_start[n], s1 = row_start[n + 1];
  const char* xb = (const char*)x;
  int loff = 8 * li;
  float a0 = 0.f, a1 = 0.f, a2 = 0.f, a3 = 0.f;
  const int2* ep = erec + s0;
  for (int e0 = s0; e0 < s1; e0 += 8, ep += 8) {
    int2 r[8];
    #pragma unroll
    for (int u = 0; u < 8; ++u) r[u] = ep[u];      // imm-offset loads off one base
    uint2 pair[8];
    #pragma unroll
    for (int u = 0; u < 8; ++u)
      pair[u] = *(const uint2*)(xb + (size_t)(uint32_t)(r[u].x + loff));
    #pragma unroll
    for (int u = 0; u < 8; ++u) {
      float w = (e0 + u < s1) ? __int_as_float(r[u].y) : 0.f;
      union { uint32_t u32; float f; } q0, q1, q2, q3;
      q0.u32 = pair[u].x << 16; q1.u32 = pair[u].x & 0xffff0000u;
      q2.u32 = pair[u].y << 16; q3.u32 = pair[u].y & 0xffff0000u;
      a0 += w * q0.f; a1 += w * q1.f; a2 += w * q2.f; a3 += w * q3.f;
    }
  }
  uint2 o;
  o.x = ((uint32_t)f2bf(a1) << 16) | (uint32_t)f2bf(a0);
  o.y = ((uint32_t)f2bf(a3) << 16) | (uint32_t)f2bf(a2);
  *(uint2*)(agg + (size_t)n*HID + 4*li) = o;
}

// ---- fused GEMM: out = relu([A1|A2] @ B^T + bias)
// 128x128 tile, 4 waves as 2(M)x2(N). Hybrid staging:
//   A fragments: straight global->register (contiguous 16B, read-once — R4-proven).
//   B tile (8KB/kt): global_load_lds into k-chunk-major LDS [chunk][j][8] so
//   ds_read_b128 across a 16-lane group is CONTIGUOUS -> zero bank conflicts
//   (old j-major layout was 8-way at 64B stride).
__global__ __launch_bounds__(256) void gemm_kernel(const uint16_t* __restrict__ A1, const uint16_t* __restrict__ A2,
                                                   const uint16_t* __restrict__ Bm, const float* __restrict__ bias,
                                                   uint16_t* __restrict__ out) {
  __shared__ uint16_t ldsB[4 * 128 * 8];   // [chunk c][j][8 elems] = 8KB
  int t = threadIdx.x;
  int n0 = blockIdx.x * 128;
  int lane = t & 63, wave = t >> 6;
  int l15 = lane & 15, quad = lane >> 4;
  int wm = (wave >> 1) * 64, wn = (wave & 1) * 64;

  uint32_t rowoff[4];
  #pragma unroll
  for (int mi = 0; mi < 4; ++mi) {
    int rowA = n0 + wm + mi * 16 + l15;
    if (rowA >= NN) rowA = NN - 1;
    rowoff[mi] = (uint32_t)rowA * HID;
  }

  f32x4 acc[4][4];
  #pragma unroll
  for (int i = 0; i < 4; ++i)
    #pragma unroll
    for (int j = 0; j < 4; ++j) acc[i][j] = (f32x4){0.f, 0.f, 0.f, 0.f};

  for (int kt = 0; kt < 8; ++kt) {
    int kbase = kt * 32;
    #pragma unroll
    for (int q = 0; q < 2; ++q) {
      int u = t + q * 256;               // 0..511: c = u>>7 (0..3), j = u&127
      int j = u & 127, c = u >> 7;
      __builtin_amdgcn_global_load_lds(AS1(Bm + j * 256 + kbase + c * 8), AS3(&ldsB[u * 8]), 16, 0, 0);
    }
    __syncthreads();
    const uint16_t* Asrc = (kt < 4) ? A1 : A2;
    int klocal = (kt & 3) * 32 + quad * 8;
    bf16x8 af[4];
    #pragma unroll
    for (int mi = 0; mi < 4; ++mi)
      af[mi] = *(const bf16x8*)(Asrc + (size_t)rowoff[mi] + klocal);
    bf16x8 bfr[4];
    #pragma unroll
    for (int ni = 0; ni < 4; ++ni) {
      int j = wn + ni * 16 + l15;        // < 128
      bfr[ni] = *(const bf16x8*)&ldsB[quad * 1024 + j * 8];
    }
    #pragma unroll
    for (int mi = 0; mi < 4; ++mi)
      #pragma unroll
      for (int ni = 0; ni < 4; ++ni)
        acc[mi][ni] = __builtin_amdgcn_mfma_f32_16x16x32_bf16(af[mi], bfr[ni], acc[mi][ni], 0, 0, 0);
    __syncthreads();
  }

  #pragma unroll
  for (int mi = 0; mi < 4; ++mi) {
    #pragma unroll
    for (int ni = 0; ni < 4; ++ni) {
      int c = wn + ni * 16 + l15;        // < 128
      float bc = bias[c];
      #pragma unroll
      for (int i = 0; i < 4; ++i) {
        int r = n0 + wm + mi * 16 + quad * 4 + i;
        if (r < NN) {
          float v = acc[mi][ni][i] + bc;
          v = v > 0.f ? v : 0.f;
          out[(size_t)r*HID + c] = f2bf(v);
        }
      }
    }
  }
}

// ---- final: logits = [x1|x2|x3] @ Wlb^T + bl ; log_softmax ; store f32
__global__ __launch_bounds__(256) void final_kernel(const uint16_t* __restrict__ x1, const uint16_t* __restrict__ x2,
                                                    const uint16_t* __restrict__ x3,
                                                    const uint16_t* __restrict__ Wlb, const float* __restrict__ bl,
                                                    float* __restrict__ out) {
  int t = threadIdx.x;
  int lane = t & 63, wave = t >> 6;
  int n0 = blockIdx.x * 64 + wave * 16;
  int l15 = lane & 15, quad = lane >> 4;

  f32x4 acc[3];
  #pragma unroll
  for (int i = 0; i < 3; ++i) acc[i] = (f32x4){0.f, 0.f, 0.f, 0.f};

  int arow = n0 + l15; if (arow >= NN) arow = NN - 1;

  #pragma unroll
  for (int kt = 0; kt < 12; ++kt) {
    const uint16_t* xs = (kt < 4) ? x1 : (kt < 8) ? x2 : x3;
    int klocal = (kt & 3) * 32 + quad * 8;
    bf16x8 af = *(const bf16x8*)(xs + (size_t)arow*HID + klocal);
    int kglob = kt * 32 + quad * 8;
    #pragma unroll
    for (int nt = 0; nt < 3; ++nt) {
      int c = nt*16 + l15;                 // < 48, row 47 of Wlb is zero
      bf16x8 bfr = *(const bf16x8*)(Wlb + (size_t)c*(3*HID) + kglob);
      acc[nt] = __builtin_amdgcn_mfma_f32_16x16x32_bf16(af, bfr, acc[nt], 0, 0, 0);
    }
  }

  float bias[3]; bool valid[3];
  #pragma unroll
  for (int nt = 0; nt < 3; ++nt) {
    int c = nt*16 + l15;
    valid[nt] = (c < CLS);
    bias[nt] = valid[nt] ? bl[c] : 0.f;
  }

  #pragma unroll
  for (int i = 0; i < 4; ++i) {
    int r = n0 + quad*4 + i;
    float v0 = acc[0][i] + bias[0];
    float v1 = acc[1][i] + bias[1];
    float v2 = valid[2] ? (acc[2][i] + bias[2]) : -INFINITY;
    float m = fmaxf(v0, fmaxf(v1, v2));
    #pragma unroll
    for (int off = 8; off >= 1; off >>= 1) m = fmaxf(m, __shfl_xor(m, off, 64));
    float s = __expf(v0 - m) + __expf(v1 - m) + (valid[2] ? __expf(v2 - m) : 0.f);
    #pragma unroll
    for (int off = 8; off >= 1; off >>= 1) s += __shfl_xor(s, off, 64);
    float lse = m + __logf(s);
    if (r < NN) {
      out[(size_t)r*CLS + l15]      = v0 - lse;
      out[(size_t)r*CLS + 16 + l15] = v1 - lse;
      if (valid[2]) out[(size_t)r*CLS + 32 + l15] = v2 - lse;
    }
  }
}

extern "C" void kernel_launch(void* const* d_in, const int* in_sizes, int n_in,
                              void* d_out, int out_size, void* d_ws, size_t ws_size,
                              hipStream_t stream) {
  (void)in_sizes; (void)n_in; (void)out_size; (void)ws_size;
  const float* x0  = (const float*)d_in[0];
  const int*   ei  = (const int*)d_in[1];
  const float* ew  = (const float*)d_in[2];
  const float* W1r = (const float*)d_in[3];
  const float* W1o = (const float*)d_in[4];
  const float* b1  = (const float*)d_in[5];
  const float* W2r = (const float*)d_in[6];
  const float* W2o = (const float*)d_in[7];
  const float* b2  = (const float*)d_in[8];
  const float* W3r = (const float*)d_in[9];
  const float* W3o = (const float*)d_in[10];
  const float* b3  = (const float*)d_in[11];
  const float* Wl  = (const float*)d_in[12];
  const float* bl  = (const float*)d_in[13];
  const int* src = ei;
  const int* dst = ei + NE;

  char* ws = (char*)d_ws;
  size_t off = 0;
  auto alloc = [&](size_t bytes) -> void* {
    void* p = ws + off;
    off += (bytes + 255) & ~(size_t)255;
    return p;
  };
  uint16_t* x0p = (uint16_t*)alloc((size_t)NN * HID * 2);   // also reused as xb2
  uint16_t* xb1 = (uint16_t*)alloc((size_t)NN * HID * 2);
  uint16_t* xb3 = (uint16_t*)alloc((size_t)NN * HID * 2);
  uint16_t* agg = (uint16_t*)alloc((size_t)NN * HID * 2);
  int2*   erec      = (int2*)alloc((size_t)(NE + 16) * 8);  // +16 zero-weight pad recs
  int2*   ebin      = (int2*)alloc((size_t)NE * 8);
  int*    row_start = (int*)alloc((size_t)(NN + 1) * 4);
  int*    bcnt      = (int*)alloc(NBUK * 4);
  int*    bfill     = (int*)alloc(NBUK * 4);
  int*    bbase     = (int*)alloc((NBUK + 1) * 4);
  uint16_t* B1 = (uint16_t*)alloc(128 * 256 * 2);
  uint16_t* B2 = (uint16_t*)alloc(128 * 256 * 2);
  uint16_t* B3 = (uint16_t*)alloc(128 * 256 * 2);
  uint16_t* Wlb = (uint16_t*)alloc(48 * 384 * 2);
  uint16_t* xb2 = x0p;   // alias: x0p dead after layer-1 GEMM

  const int TB = (NE + 8191) / 8192;      // 196 tiles

  hipMemsetAsync(bcnt, 0, NBUK * 4, stream);
  hipMemsetAsync(erec + NE, 0, 16 * sizeof(int2), stream);  // pad: w=0, offset 0
  pack_weights<<<384, 256, 0, stream>>>(W1r, W1o, W2r, W2o, W3r, W3o, B1, B2, B3);
  pack_wl<<<72, 256, 0, stream>>>(Wl, Wlb);
  pad_x0<<<NN / 4, 256, 0, stream>>>(x0, x0p);
  bucket_hist<<<TB, 512, 0, stream>>>(dst, bcnt);
  bucket_scan<<<1, 512, 0, stream>>>(bcnt, bfill, bbase);
  binscat<<<TB, 512, 0, stream>>>(src, dst, ew, bfill, ebin);
  bucket_csr<<<NBUK, 256, 0, stream>>>(ebin, bbase, row_start, erec);

  spmm_kernel<<<NN / 8, 256, 0, stream>>>(x0p, row_start, erec, agg);
  gemm_kernel<<<(NN + 127) / 128, 256, 0, stream>>>(agg, x0p, B1, b1, xb1);
  spmm_kernel<<<NN / 8, 256, 0, stream>>>(xb1, row_start, erec, agg);
  gemm_kernel<<<(NN + 127) / 128, 256, 0, stream>>>(agg, xb1, B2, b2, xb2);
  spmm_kernel<<<NN / 8, 256, 0, stream>>>(xb2, row_start, erec, agg);
  gemm_kernel<<<(NN + 127) / 128, 256, 0, stream>>>(agg, xb2, B3, b3, xb3);

  final_kernel<<<(NN + 63) / 64, 256, 0, stream>>>(xb1, xb2, xb3, Wlb, bl, (float*)d_out);
}

// Round 6
// 422.623 us; speedup vs baseline: 1.3252x; 1.2410x over previous
//
#include <hip/hip_runtime.h>
#include <hip/hip_bf16.h>
#include <stdint.h>

#define NN 100000
#define NE 1600000
#define FIN 100
#define HID 128
#define CLS 47
#define NBUK 391            // ceil(NN/256) buckets of 256 nodes

typedef __attribute__((ext_vector_type(8))) short bf16x8;
typedef __attribute__((ext_vector_type(4))) float f32x4;
typedef __attribute__((ext_vector_type(2))) float f32x2;

#define AS1(p) ((const __attribute__((address_space(1))) void*)(p))
#define AS3(p) ((__attribute__((address_space(3))) void*)(p))

__device__ __forceinline__ uint16_t f2bf(float f) {
  union { float f; uint32_t u; } v; v.f = f;
  uint32_t r = v.u + 0x7fffu + ((v.u >> 16) & 1u);
  return (uint16_t)(r >> 16);
}

// ---- weight packing: B_l[j][k] (128 x 256) bf16; k<128 -> W_rel, k>=128 -> W_root (layer1 zero-padded)
__global__ void pack_weights(const float* __restrict__ W1r, const float* __restrict__ W1o,
                             const float* __restrict__ W2r, const float* __restrict__ W2o,
                             const float* __restrict__ W3r, const float* __restrict__ W3o,
                             uint16_t* __restrict__ B1, uint16_t* __restrict__ B2, uint16_t* __restrict__ B3) {
  int idx = blockIdx.x * 256 + threadIdx.x;      // < 3*128*256
  int l = idx >> 15;
  int rem = idx & 32767;
  int j = rem >> 8;
  int k = rem & 255;
  if (l == 0) {
    uint16_t v = 0;
    if (k < FIN) v = f2bf(W1r[j*FIN + k]);
    else if (k >= 128 && k < 128 + FIN) v = f2bf(W1o[j*FIN + (k - 128)]);
    B1[j*256 + k] = v;
  } else if (l == 1) {
    B2[j*256 + k] = (k < 128) ? f2bf(W2r[j*128 + k]) : f2bf(W2o[j*128 + (k - 128)]);
  } else {
    B3[j*256 + k] = (k < 128) ? f2bf(W3r[j*128 + k]) : f2bf(W3o[j*128 + (k - 128)]);
  }
}

// ---- W_lin [47,384] f32 -> Wlb [48,384] bf16 (row 47 zero)
__global__ void pack_wl(const float* __restrict__ Wl, uint16_t* __restrict__ Wlb) {
  int idx = blockIdx.x * 256 + threadIdx.x;      // < 48*384
  int r = idx / 384;
  int c = idx - r * 384;
  Wlb[idx] = (r < CLS) ? f2bf(Wl[r*384 + c]) : (uint16_t)0;
}

// ---- pad+convert x0 [N,100] f32 -> x0p [N,128] bf16 AND x0f8 [N,128] fp8 (zeros past col 99)
__global__ __launch_bounds__(256) void pad_x0(const float* __restrict__ x0, uint16_t* __restrict__ x0p,
                                              uint8_t* __restrict__ x0f8) {
  int n = blockIdx.x * 4 + (threadIdx.x >> 6);
  int c = 2 * (threadIdx.x & 63);
  uint32_t o = 0;
  uint16_t o8 = 0;
  if (c < FIN) {
    float2 v = *(const float2*)(x0 + (size_t)n*FIN + c);
    o = ((uint32_t)f2bf(v.y) << 16) | (uint32_t)f2bf(v.x);
    o8 = (uint16_t)__builtin_amdgcn_cvt_pk_fp8_f32(v.x, v.y, 0, false);
  }
  *(uint32_t*)(x0p + (size_t)n*HID + c) = o;
  *(uint16_t*)(x0f8 + (size_t)n*128 + c) = o8;
}

// ======== binned CSR build (write-coalescing-aware) ========
// Stage 1: per-bucket counts via LDS pre-aggregation (196 blocks x 8192-edge tiles)
__global__ __launch_bounds__(512) void bucket_hist(const int* __restrict__ dst, int* __restrict__ bcnt) {
  __shared__ int h[NBUK];
  int tid = threadIdx.x;
  for (int i = tid; i < NBUK; i += 512) h[i] = 0;
  __syncthreads();
  int tile0 = blockIdx.x * 8192;
  int n = NE - tile0; if (n > 8192) n = 8192;
  for (int i = tid; i < n; i += 512) atomicAdd(&h[dst[tile0 + i] >> 8], 1);
  __syncthreads();
  for (int i = tid; i < NBUK; i += 512) if (h[i]) atomicAdd(&bcnt[i], h[i]);
}

// Stage 2: exclusive scan of 391 bucket counts -> bases (fill = working copy)
__global__ __launch_bounds__(512) void bucket_scan(const int* __restrict__ bcnt,
                                                   int* __restrict__ bfill, int* __restrict__ bbase) {
  __shared__ int sh[512];
  int t = threadIdx.x;
  int v = (t < NBUK) ? bcnt[t] : 0;
  sh[t] = v;
  __syncthreads();
  for (int off = 1; off < 512; off <<= 1) {
    int tv = (t >= off) ? sh[t - off] : 0;
    __syncthreads();
    sh[t] += tv;
    __syncthreads();
  }
  if (t < NBUK) {
    int e = sh[t] - v;
    bfill[t] = e;
    bbase[t] = e;
  }
  if (t == 0) bbase[NBUK] = NE;
}

// Stage 3: binned scatter. Each block claims contiguous per-bucket chunks so all
// writes to a chunk come from ONE CU -> L2 write-combining -> full-line writebacks.
// Packed rec: x = src | dstLocal<<17 (src<2^17, dstLocal<256), y = weight bits.
__global__ __launch_bounds__(512) void binscat(const int* __restrict__ src, const int* __restrict__ dst,
                                               const float* __restrict__ ew,
                                               int* __restrict__ bfill, int2* __restrict__ ebin) {
  __shared__ int h[NBUK];
  __shared__ int base[NBUK];
  int tid = threadIdx.x;
  for (int i = tid; i < NBUK; i += 512) h[i] = 0;
  __syncthreads();
  int tile0 = blockIdx.x * 8192;
  int n = NE - tile0; if (n > 8192) n = 8192;
  for (int i = tid; i < n; i += 512) atomicAdd(&h[dst[tile0 + i] >> 8], 1);
  __syncthreads();
  for (int i = tid; i < NBUK; i += 512) base[i] = h[i] ? atomicAdd(&bfill[i], h[i]) : 0;
  __syncthreads();
  for (int i = tid; i < NBUK; i += 512) h[i] = 0;
  __syncthreads();
  for (int i = tid; i < n; i += 512) {
    int e = tile0 + i;
    int d = dst[e];
    int b = d >> 8;
    int r = atomicAdd(&h[b], 1);
    ebin[base[b] + r] = make_int2(src[e] | ((d & 255) << 17), __float_as_int(ew[e]));
  }
}

// Stage 4: one block per bucket. LDS hist+scan over the 256 local nodes gives
// row_start directly, then scatters the final erec {src byte-offset (fp8 row=128B), weight}
// within this bucket's ~33KB window — single CU => coalesced writebacks.
__global__ __launch_bounds__(256) void bucket_csr(const int2* __restrict__ ebin,
                                                  const int* __restrict__ bbase,
                                                  int* __restrict__ row_start,
                                                  int2* __restrict__ erec) {
  __shared__ int sh[256];
  __shared__ int fill[256];
  int b = blockIdx.x;
  int tid = threadIdx.x;
  int ebase = bbase[b], eend = bbase[b + 1];
  int cnt = eend - ebase;
  sh[tid] = 0;
  __syncthreads();
  for (int i = tid; i < cnt; i += 256) atomicAdd(&sh[(uint32_t)ebin[ebase + i].x >> 17], 1);
  __syncthreads();
  int histv = sh[tid];
  __syncthreads();
  for (int off = 1; off < 256; off <<= 1) {
    int tv = (tid >= off) ? sh[tid - off] : 0;
    __syncthreads();
    sh[tid] += tv;
    __syncthreads();
  }
  int excl = sh[tid] - histv;
  int node = b * 256 + tid;
  if (node <= NN) row_start[node] = ebase + excl;   // node==NN -> ebase+cnt == NE
  fill[tid] = ebase + excl;
  __syncthreads();
  for (int i = tid; i < cnt; i += 256) {
    int2 rec = ebin[ebase + i];
    int dl = (uint32_t)rec.x >> 17;
    int s = rec.x & 0x1FFFF;
    int pos = atomicAdd(&fill[dl], 1);
    erec[pos] = make_int2(s << 7, rec.y);           // s*128 = byte offset into fp8 row
  }
}

// ---- SpMM: agg[n,:] = sum_{e in row n} w_e * x8[src_e,:]  (x8 = fp8 e4m3 rows, 128B = 1 line)
// Two nodes per wave: each 32-lane half owns its OWN row and edge stream.
// Lane covers 4 cols (4B); batches of 8 edges -> 16 one-line gathers in flight per wave.
__global__ __launch_bounds__(256) void spmm_kernel(const uint8_t* __restrict__ x8,
                                                   const int* __restrict__ row_start,
                                                   const int2* __restrict__ erec,
                                                   uint16_t* __restrict__ agg) {
  int wave = threadIdx.x >> 6;
  int l = threadIdx.x & 63;
  int half = l >> 5, li = l & 31;
  int n = blockIdx.x * 8 + wave * 2 + half;
  int s0 = row_start[n], s1 = row_start[n + 1];
  const char* xb = (const char*)x8;
  int loff = 4 * li;
  float a0 = 0.f, a1 = 0.f, a2 = 0.f, a3 = 0.f;
  const int2* ep = erec + s0;
  for (int e0 = s0; e0 < s1; e0 += 8, ep += 8) {
    int2 r[8];
    #pragma unroll
    for (int u = 0; u < 8; ++u) r[u] = ep[u];      // imm-offset loads off one base
    uint32_t g[8];
    #pragma unroll
    for (int u = 0; u < 8; ++u)
      g[u] = *(const uint32_t*)(xb + (size_t)(uint32_t)(r[u].x + loff));
    #pragma unroll
    for (int u = 0; u < 8; ++u) {
      float w = (e0 + u < s1) ? __int_as_float(r[u].y) : 0.f;
      f32x2 lo = __builtin_amdgcn_cvt_pk_f32_fp8(g[u], false);
      f32x2 hi = __builtin_amdgcn_cvt_pk_f32_fp8(g[u], true);
      a0 += w * lo[0]; a1 += w * lo[1]; a2 += w * hi[0]; a3 += w * hi[1];
    }
  }
  uint2 o;
  o.x = ((uint32_t)f2bf(a1) << 16) | (uint32_t)f2bf(a0);
  o.y = ((uint32_t)f2bf(a3) << 16) | (uint32_t)f2bf(a2);
  *(uint2*)(agg + (size_t)n*HID + 4*li) = o;
}

// ---- fused GEMM (R1-measured-best structure): out = relu([A1|A2] @ B^T + bias)
// A and B tiles both staged per kt via global_load_lds; optional fp8 copy of out.
__global__ __launch_bounds__(256) void gemm_kernel(const uint16_t* __restrict__ A1, const uint16_t* __restrict__ A2,
                                                   const uint16_t* __restrict__ Bm, const float* __restrict__ bias,
                                                   uint16_t* __restrict__ out, uint8_t* __restrict__ out8) {
  __shared__ uint16_t ldsA[128 * 32];
  __shared__ uint16_t ldsB[128 * 32];
  int t = threadIdx.x;
  int n0 = blockIdx.x * 128;
  int lane = t & 63, wave = t >> 6;
  int wm = (wave >> 1) * 64, wn = (wave & 1) * 64;
  int l15 = lane & 15, quad = lane >> 4;

  f32x4 acc[4][4];
  #pragma unroll
  for (int i = 0; i < 4; ++i)
    #pragma unroll
    for (int j = 0; j < 4; ++j) acc[i][j] = (f32x4){0.f, 0.f, 0.f, 0.f};

  for (int kt = 0; kt < 8; ++kt) {
    int kbase = kt * 32;
    const uint16_t* Asrc = (kbase < 128) ? A1 : A2;
    int klocal = kbase & 127;
    #pragma unroll
    for (int q = 0; q < 2; ++q) {
      int u = t + q * 256;                 // 0..511
      int r = u >> 2;                      // 0..127
      int kg = (u & 3) * 8;
      int rowA = n0 + r; if (rowA >= NN) rowA = NN - 1;
      __builtin_amdgcn_global_load_lds(AS1(Asrc + (size_t)rowA*HID + klocal + kg), AS3(&ldsA[u * 8]), 16, 0, 0);
      __builtin_amdgcn_global_load_lds(AS1(Bm + r*256 + kbase + kg), AS3(&ldsB[u * 8]), 16, 0, 0);
    }
    __syncthreads();
    bf16x8 af[4], bfr[4];
    #pragma unroll
    for (int mi = 0; mi < 4; ++mi) af[mi] = *(const bf16x8*)&ldsA[(wm + mi*16 + l15) * 32 + quad * 8];
    #pragma unroll
    for (int ni = 0; ni < 4; ++ni) bfr[ni] = *(const bf16x8*)&ldsB[(wn + ni*16 + l15) * 32 + quad * 8];
    #pragma unroll
    for (int mi = 0; mi < 4; ++mi)
      #pragma unroll
      for (int ni = 0; ni < 4; ++ni)
        acc[mi][ni] = __builtin_amdgcn_mfma_f32_16x16x32_bf16(af[mi], bfr[ni], acc[mi][ni], 0, 0, 0);
    __syncthreads();
  }

  #pragma unroll
  for (int mi = 0; mi < 4; ++mi) {
    #pragma unroll
    for (int ni = 0; ni < 4; ++ni) {
      int c = wn + ni*16 + l15;
      float bc = bias[c];
      #pragma unroll
      for (int i = 0; i < 4; ++i) {
        int r = n0 + wm + mi*16 + quad*4 + i;
        if (r < NN) {
          float v = acc[mi][ni][i] + bc;
          v = v > 0.f ? v : 0.f;
          out[(size_t)r*HID + c] = f2bf(v);
          if (out8) out8[(size_t)r*128 + c] = (uint8_t)__builtin_amdgcn_cvt_pk_fp8_f32(v, v, 0, false);
        }
      }
    }
  }
}

// ---- final: logits = [x1|x2|x3] @ Wlb^T + bl ; log_softmax ; store f32
__global__ __launch_bounds__(256) void final_kernel(const uint16_t* __restrict__ x1, const uint16_t* __restrict__ x2,
                                                    const uint16_t* __restrict__ x3,
                                                    const uint16_t* __restrict__ Wlb, const float* __restrict__ bl,
                                                    float* __restrict__ out) {
  int t = threadIdx.x;
  int lane = t & 63, wave = t >> 6;
  int n0 = blockIdx.x * 64 + wave * 16;
  int l15 = lane & 15, quad = lane >> 4;

  f32x4 acc[3];
  #pragma unroll
  for (int i = 0; i < 3; ++i) acc[i] = (f32x4){0.f, 0.f, 0.f, 0.f};

  int arow = n0 + l15; if (arow >= NN) arow = NN - 1;

  #pragma unroll
  for (int kt = 0; kt < 12; ++kt) {
    const uint16_t* xs = (kt < 4) ? x1 : (kt < 8) ? x2 : x3;
    int klocal = (kt & 3) * 32 + quad * 8;
    bf16x8 af = *(const bf16x8*)(xs + (size_t)arow*HID + klocal);
    int kglob = kt * 32 + quad * 8;
    #pragma unroll
    for (int nt = 0; nt < 3; ++nt) {
      int c = nt*16 + l15;                 // < 48, row 47 of Wlb is zero
      bf16x8 bfr = *(const bf16x8*)(Wlb + (size_t)c*(3*HID) + kglob);
      acc[nt] = __builtin_amdgcn_mfma_f32_16x16x32_bf16(af, bfr, acc[nt], 0, 0, 0);
    }
  }

  float bias[3]; bool valid[3];
  #pragma unroll
  for (int nt = 0; nt < 3; ++nt) {
    int c = nt*16 + l15;
    valid[nt] = (c < CLS);
    bias[nt] = valid[nt] ? bl[c] : 0.f;
  }

  #pragma unroll
  for (int i = 0; i < 4; ++i) {
    int r = n0 + quad*4 + i;
    float v0 = acc[0][i] + bias[0];
    float v1 = acc[1][i] + bias[1];
    float v2 = valid[2] ? (acc[2][i] + bias[2]) : -INFINITY;
    float m = fmaxf(v0, fmaxf(v1, v2));
    #pragma unroll
    for (int off = 8; off >= 1; off >>= 1) m = fmaxf(m, __shfl_xor(m, off, 64));
    float s = __expf(v0 - m) + __expf(v1 - m) + (valid[2] ? __expf(v2 - m) : 0.f);
    #pragma unroll
    for (int off = 8; off >= 1; off >>= 1) s += __shfl_xor(s, off, 64);
    float lse = m + __logf(s);
    if (r < NN) {
      out[(size_t)r*CLS + l15]      = v0 - lse;
      out[(size_t)r*CLS + 16 + l15] = v1 - lse;
      if (valid[2]) out[(size_t)r*CLS + 32 + l15] = v2 - lse;
    }
  }
}

extern "C" void kernel_launch(void* const* d_in, const int* in_sizes, int n_in,
                              void* d_out, int out_size, void* d_ws, size_t ws_size,
                              hipStream_t stream) {
  (void)in_sizes; (void)n_in; (void)out_size; (void)ws_size;
  const float* x0  = (const float*)d_in[0];
  const int*   ei  = (const int*)d_in[1];
  const float* ew  = (const float*)d_in[2];
  const float* W1r = (const float*)d_in[3];
  const float* W1o = (const float*)d_in[4];
  const float* b1  = (const float*)d_in[5];
  const float* W2r = (const float*)d_in[6];
  const float* W2o = (const float*)d_in[7];
  const float* b2  = (const float*)d_in[8];
  const float* W3r = (const float*)d_in[9];
  const float* W3o = (const float*)d_in[10];
  const float* b3  = (const float*)d_in[11];
  const float* Wl  = (const float*)d_in[12];
  const float* bl  = (const float*)d_in[13];
  const int* src = ei;
  const int* dst = ei + NE;

  char* ws = (char*)d_ws;
  size_t off = 0;
  auto alloc = [&](size_t bytes) -> void* {
    void* p = ws + off;
    off += (bytes + 255) & ~(size_t)255;
    return p;
  };
  uint16_t* x0p = (uint16_t*)alloc((size_t)NN * HID * 2);   // also reused as xb2
  uint16_t* xb1 = (uint16_t*)alloc((size_t)NN * HID * 2);
  uint16_t* xb3 = (uint16_t*)alloc((size_t)NN * HID * 2);
  uint16_t* agg = (uint16_t*)alloc((size_t)NN * HID * 2);
  int2*   erec      = (int2*)alloc((size_t)(NE + 16) * 8);  // +16 zero-weight pad recs
  int2*   ebin      = (int2*)alloc((size_t)NE * 8);         // dead after bucket_csr -> reused as xb1f8
  int*    row_start = (int*)alloc((size_t)(NN + 1) * 4);
  int*    bcnt      = (int*)alloc(NBUK * 4);
  int*    bfill     = (int*)alloc(NBUK * 4);
  int*    bbase     = (int*)alloc((NBUK + 1) * 4);
  uint16_t* B1 = (uint16_t*)alloc(128 * 256 * 2);
  uint16_t* B2 = (uint16_t*)alloc(128 * 256 * 2);
  uint16_t* B3 = (uint16_t*)alloc(128 * 256 * 2);
  uint16_t* Wlb = (uint16_t*)alloc(48 * 384 * 2);
  uint8_t* x0f8  = (uint8_t*)alloc((size_t)NN * 128);
  uint8_t* xb2f8 = (uint8_t*)alloc((size_t)NN * 128);
  uint16_t* xb2 = x0p;                 // alias: x0p dead after layer-1 GEMM
  uint8_t* xb1f8 = (uint8_t*)ebin;     // alias: ebin dead after bucket_csr (NE*8 >= NN*128)

  const int TB = (NE + 8191) / 8192;      // 196 tiles

  hipMemsetAsync(bcnt, 0, NBUK * 4, stream);
  hipMemsetAsync(erec + NE, 0, 16 * sizeof(int2), stream);  // pad: w=0, offset 0
  pack_weights<<<384, 256, 0, stream>>>(W1r, W1o, W2r, W2o, W3r, W3o, B1, B2, B3);
  pack_wl<<<72, 256, 0, stream>>>(Wl, Wlb);
  pad_x0<<<NN / 4, 256, 0, stream>>>(x0, x0p, x0f8);
  bucket_hist<<<TB, 512, 0, stream>>>(dst, bcnt);
  bucket_scan<<<1, 512, 0, stream>>>(bcnt, bfill, bbase);
  binscat<<<TB, 512, 0, stream>>>(src, dst, ew, bfill, ebin);
  bucket_csr<<<NBUK, 256, 0, stream>>>(ebin, bbase, row_start, erec);

  spmm_kernel<<<NN / 8, 256, 0, stream>>>(x0f8, row_start, erec, agg);
  gemm_kernel<<<(NN + 127) / 128, 256, 0, stream>>>(agg, x0p, B1, b1, xb1, xb1f8);
  spmm_kernel<<<NN / 8, 256, 0, stream>>>(xb1f8, row_start, erec, agg);
  gemm_kernel<<<(NN + 127) / 128, 256, 0, stream>>>(agg, xb1, B2, b2, xb2, xb2f8);
  spmm_kernel<<<NN / 8, 256, 0, stream>>>(xb2f8, row_start, erec, agg);
  gemm_kernel<<<(NN + 127) / 128, 256, 0, stream>>>(agg, xb2, B3, b3, xb3, nullptr);

  final_kernel<<<(NN + 63) / 64, 256, 0, stream>>>(xb1, xb2, xb3, Wlb, bl, (float*)d_out);
}

// Round 7
// 414.502 us; speedup vs baseline: 1.3512x; 1.0196x over previous
//
#include <hip/hip_runtime.h>
#include <hip/hip_bf16.h>
#include <stdint.h>

#define NN 100000
#define NE 1600000
#define FIN 100
#define HID 128
#define CLS 47
#define NBUK 391            // ceil(NN/256) buckets of 256 nodes

typedef __attribute__((ext_vector_type(8))) short bf16x8;
typedef __attribute__((ext_vector_type(4))) float f32x4;
typedef __attribute__((ext_vector_type(2))) float f32x2;

#define AS1(p) ((const __attribute__((address_space(1))) void*)(p))
#define AS3(p) ((__attribute__((address_space(3))) void*)(p))

__device__ __forceinline__ uint16_t f2bf(float f) {
  union { float f; uint32_t u; } v; v.f = f;
  uint32_t r = v.u + 0x7fffu + ((v.u >> 16) & 1u);
  return (uint16_t)(r >> 16);
}

// ---- weight packing: B_l[j][k] (128 x 256) bf16; k<128 -> W_rel, k>=128 -> W_root (layer1 zero-padded)
__global__ void pack_weights(const float* __restrict__ W1r, const float* __restrict__ W1o,
                             const float* __restrict__ W2r, const float* __restrict__ W2o,
                             const float* __restrict__ W3r, const float* __restrict__ W3o,
                             uint16_t* __restrict__ B1, uint16_t* __restrict__ B2, uint16_t* __restrict__ B3) {
  int idx = blockIdx.x * 256 + threadIdx.x;      // < 3*128*256
  int l = idx >> 15;
  int rem = idx & 32767;
  int j = rem >> 8;
  int k = rem & 255;
  if (l == 0) {
    uint16_t v = 0;
    if (k < FIN) v = f2bf(W1r[j*FIN + k]);
    else if (k >= 128 && k < 128 + FIN) v = f2bf(W1o[j*FIN + (k - 128)]);
    B1[j*256 + k] = v;
  } else if (l == 1) {
    B2[j*256 + k] = (k < 128) ? f2bf(W2r[j*128 + k]) : f2bf(W2o[j*128 + (k - 128)]);
  } else {
    B3[j*256 + k] = (k < 128) ? f2bf(W3r[j*128 + k]) : f2bf(W3o[j*128 + (k - 128)]);
  }
}

// ---- W_lin [47,384] f32 -> Wlb [48,384] bf16 (row 47 zero)
__global__ void pack_wl(const float* __restrict__ Wl, uint16_t* __restrict__ Wlb) {
  int idx = blockIdx.x * 256 + threadIdx.x;      // < 48*384
  int r = idx / 384;
  int c = idx - r * 384;
  Wlb[idx] = (r < CLS) ? f2bf(Wl[r*384 + c]) : (uint16_t)0;
}

// ---- pad+convert x0 [N,100] f32 -> x0p [N,128] bf16 AND x0f8 [N,128] fp8 (zeros past col 99)
__global__ __launch_bounds__(256) void pad_x0(const float* __restrict__ x0, uint16_t* __restrict__ x0p,
                                              uint8_t* __restrict__ x0f8) {
  int n = blockIdx.x * 4 + (threadIdx.x >> 6);
  int c = 2 * (threadIdx.x & 63);
  uint32_t o = 0;
  uint16_t o8 = 0;
  if (c < FIN) {
    float2 v = *(const float2*)(x0 + (size_t)n*FIN + c);
    o = ((uint32_t)f2bf(v.y) << 16) | (uint32_t)f2bf(v.x);
    o8 = (uint16_t)__builtin_amdgcn_cvt_pk_fp8_f32(v.x, v.y, 0, false);
  }
  *(uint32_t*)(x0p + (size_t)n*HID + c) = o;
  *(uint16_t*)(x0f8 + (size_t)n*128 + c) = o8;
}

// ======== binned CSR build (write-coalescing-aware) ========
// Stage 1: per-bucket counts via LDS pre-aggregation (196 blocks x 8192-edge tiles)
__global__ __launch_bounds__(512) void bucket_hist(const int* __restrict__ dst, int* __restrict__ bcnt) {
  __shared__ int h[NBUK];
  int tid = threadIdx.x;
  for (int i = tid; i < NBUK; i += 512) h[i] = 0;
  __syncthreads();
  int tile0 = blockIdx.x * 8192;
  int n = NE - tile0; if (n > 8192) n = 8192;
  for (int i = tid; i < n; i += 512) atomicAdd(&h[dst[tile0 + i] >> 8], 1);
  __syncthreads();
  for (int i = tid; i < NBUK; i += 512) if (h[i]) atomicAdd(&bcnt[i], h[i]);
}

// Stage 2: exclusive scan of 391 bucket counts -> bases (fill = working copy)
__global__ __launch_bounds__(512) void bucket_scan(const int* __restrict__ bcnt,
                                                   int* __restrict__ bfill, int* __restrict__ bbase) {
  __shared__ int sh[512];
  int t = threadIdx.x;
  int v = (t < NBUK) ? bcnt[t] : 0;
  sh[t] = v;
  __syncthreads();
  for (int off = 1; off < 512; off <<= 1) {
    int tv = (t >= off) ? sh[t - off] : 0;
    __syncthreads();
    sh[t] += tv;
    __syncthreads();
  }
  if (t < NBUK) {
    int e = sh[t] - v;
    bfill[t] = e;
    bbase[t] = e;
  }
  if (t == 0) bbase[NBUK] = NE;
}

// Stage 3: binned scatter. Each block claims contiguous per-bucket chunks so all
// writes to a chunk come from ONE CU -> L2 write-combining -> full-line writebacks.
// Packed rec: x = src | dstLocal<<17 (src<2^17, dstLocal<256), y = weight bits.
__global__ __launch_bounds__(512) void binscat(const int* __restrict__ src, const int* __restrict__ dst,
                                               const float* __restrict__ ew,
                                               int* __restrict__ bfill, int2* __restrict__ ebin) {
  __shared__ int h[NBUK];
  __shared__ int base[NBUK];
  int tid = threadIdx.x;
  for (int i = tid; i < NBUK; i += 512) h[i] = 0;
  __syncthreads();
  int tile0 = blockIdx.x * 8192;
  int n = NE - tile0; if (n > 8192) n = 8192;
  for (int i = tid; i < n; i += 512) atomicAdd(&h[dst[tile0 + i] >> 8], 1);
  __syncthreads();
  for (int i = tid; i < NBUK; i += 512) base[i] = h[i] ? atomicAdd(&bfill[i], h[i]) : 0;
  __syncthreads();
  for (int i = tid; i < NBUK; i += 512) h[i] = 0;
  __syncthreads();
  for (int i = tid; i < n; i += 512) {
    int e = tile0 + i;
    int d = dst[e];
    int b = d >> 8;
    int r = atomicAdd(&h[b], 1);
    ebin[base[b] + r] = make_int2(src[e] | ((d & 255) << 17), __float_as_int(ew[e]));
  }
}

// Stage 4: one block per bucket. LDS hist+scan over the 256 local nodes gives
// row_start directly, then scatters the final erec {src byte-offset (fp8 row=128B), weight}
// within this bucket's ~33KB window — single CU => coalesced writebacks.
__global__ __launch_bounds__(256) void bucket_csr(const int2* __restrict__ ebin,
                                                  const int* __restrict__ bbase,
                                                  int* __restrict__ row_start,
                                                  int2* __restrict__ erec) {
  __shared__ int sh[256];
  __shared__ int fill[256];
  int b = blockIdx.x;
  int tid = threadIdx.x;
  int ebase = bbase[b], eend = bbase[b + 1];
  int cnt = eend - ebase;
  sh[tid] = 0;
  __syncthreads();
  for (int i = tid; i < cnt; i += 256) atomicAdd(&sh[(uint32_t)ebin[ebase + i].x >> 17], 1);
  __syncthreads();
  int histv = sh[tid];
  __syncthreads();
  for (int off = 1; off < 256; off <<= 1) {
    int tv = (tid >= off) ? sh[tid - off] : 0;
    __syncthreads();
    sh[tid] += tv;
    __syncthreads();
  }
  int excl = sh[tid] - histv;
  int node = b * 256 + tid;
  if (node <= NN) row_start[node] = ebase + excl;   // node==NN -> ebase+cnt == NE
  fill[tid] = ebase + excl;
  __syncthreads();
  for (int i = tid; i < cnt; i += 256) {
    int2 rec = ebin[ebase + i];
    int dl = (uint32_t)rec.x >> 17;
    int s = rec.x & 0x1FFFF;
    int pos = atomicAdd(&fill[dl], 1);
    erec[pos] = make_int2(s << 7, rec.y);           // s*128 = byte offset into fp8 row
  }
}

// ---- SpMM: agg[n,:] = sum_{e in row n} w_e * x8[src_e,:]  (x8 = fp8 e4m3 rows, 128B = 1 line)
// Two nodes per wave (half owns its row+stream); lane covers 4 cols (4B).
// Batches of 16 edges -> 32 one-line gathers in flight per wave.
__global__ __launch_bounds__(256) void spmm_kernel(const uint8_t* __restrict__ x8,
                                                   const int* __restrict__ row_start,
                                                   const int2* __restrict__ erec,
                                                   uint16_t* __restrict__ agg) {
  int wave = threadIdx.x >> 6;
  int l = threadIdx.x & 63;
  int half = l >> 5, li = l & 31;
  int n = blockIdx.x * 8 + wave * 2 + half;
  int s0 = row_start[n], s1 = row_start[n + 1];
  const char* xb = (const char*)x8;
  int loff = 4 * li;
  float a0 = 0.f, a1 = 0.f, a2 = 0.f, a3 = 0.f;
  const int2* ep = erec + s0;
  for (int e0 = s0; e0 < s1; e0 += 16, ep += 16) {
    int2 r[16];
    #pragma unroll
    for (int u = 0; u < 16; ++u) r[u] = ep[u];     // imm-offset loads off one base
    uint32_t g[16];
    #pragma unroll
    for (int u = 0; u < 16; ++u)
      g[u] = *(const uint32_t*)(xb + (size_t)(uint32_t)(r[u].x + loff));
    #pragma unroll
    for (int u = 0; u < 16; ++u) {
      float w = (e0 + u < s1) ? __int_as_float(r[u].y) : 0.f;
      f32x2 lo = __builtin_amdgcn_cvt_pk_f32_fp8(g[u], false);
      f32x2 hi = __builtin_amdgcn_cvt_pk_f32_fp8(g[u], true);
      a0 += w * lo[0]; a1 += w * lo[1]; a2 += w * hi[0]; a3 += w * hi[1];
    }
  }
  uint2 o;
  o.x = ((uint32_t)f2bf(a1) << 16) | (uint32_t)f2bf(a0);
  o.y = ((uint32_t)f2bf(a3) << 16) | (uint32_t)f2bf(a2);
  *(uint2*)(agg + (size_t)n*HID + 4*li) = o;
}

// ---- fused GEMM (R1-measured-best structure): out = relu([A1|A2] @ B^T + bias)
// A and B tiles both staged per kt via global_load_lds; optional fp8 copy of out.
__global__ __launch_bounds__(256) void gemm_kernel(const uint16_t* __restrict__ A1, const uint16_t* __restrict__ A2,
                                                   const uint16_t* __restrict__ Bm, const float* __restrict__ bias,
                                                   uint16_t* __restrict__ out, uint8_t* __restrict__ out8) {
  __shared__ uint16_t ldsA[128 * 32];
  __shared__ uint16_t ldsB[128 * 32];
  int t = threadIdx.x;
  int n0 = blockIdx.x * 128;
  int lane = t & 63, wave = t >> 6;
  int wm = (wave >> 1) * 64, wn = (wave & 1) * 64;
  int l15 = lane & 15, quad = lane >> 4;

  f32x4 acc[4][4];
  #pragma unroll
  for (int i = 0; i < 4; ++i)
    #pragma unroll
    for (int j = 0; j < 4; ++j) acc[i][j] = (f32x4){0.f, 0.f, 0.f, 0.f};

  for (int kt = 0; kt < 8; ++kt) {
    int kbase = kt * 32;
    const uint16_t* Asrc = (kbase < 128) ? A1 : A2;
    int klocal = kbase & 127;
    #pragma unroll
    for (int q = 0; q < 2; ++q) {
      int u = t + q * 256;                 // 0..511
      int r = u >> 2;                      // 0..127
      int kg = (u & 3) * 8;
      int rowA = n0 + r; if (rowA >= NN) rowA = NN - 1;
      __builtin_amdgcn_global_load_lds(AS1(Asrc + (size_t)rowA*HID + klocal + kg), AS3(&ldsA[u * 8]), 16, 0, 0);
      __builtin_amdgcn_global_load_lds(AS1(Bm + r*256 + kbase + kg), AS3(&ldsB[u * 8]), 16, 0, 0);
    }
    __syncthreads();
    bf16x8 af[4], bfr[4];
    #pragma unroll
    for (int mi = 0; mi < 4; ++mi) af[mi] = *(const bf16x8*)&ldsA[(wm + mi*16 + l15) * 32 + quad * 8];
    #pragma unroll
    for (int ni = 0; ni < 4; ++ni) bfr[ni] = *(const bf16x8*)&ldsB[(wn + ni*16 + l15) * 32 + quad * 8];
    #pragma unroll
    for (int mi = 0; mi < 4; ++mi)
      #pragma unroll
      for (int ni = 0; ni < 4; ++ni)
        acc[mi][ni] = __builtin_amdgcn_mfma_f32_16x16x32_bf16(af[mi], bfr[ni], acc[mi][ni], 0, 0, 0);
    __syncthreads();
  }

  #pragma unroll
  for (int mi = 0; mi < 4; ++mi) {
    #pragma unroll
    for (int ni = 0; ni < 4; ++ni) {
      int c = wn + ni*16 + l15;
      float bc = bias[c];
      #pragma unroll
      for (int i = 0; i < 4; ++i) {
        int r = n0 + wm + mi*16 + quad*4 + i;
        if (r < NN) {
          float v = acc[mi][ni][i] + bc;
          v = v > 0.f ? v : 0.f;
          out[(size_t)r*HID + c] = f2bf(v);
          if (out8) out8[(size_t)r*128 + c] = (uint8_t)__builtin_amdgcn_cvt_pk_fp8_f32(v, v, 0, false);
        }
      }
    }
  }
}

// ---- final: logits = [x1|x2|x3] @ Wlb^T + bl ; log_softmax ; store f32
// LDS-staged (gemm-proven structure): per kt, stage A-tile 64x32 and W-tile 64x32
// via global_load_lds into [chunk][row][8] layouts -> 16-lane-contiguous ds_read_b128.
__global__ __launch_bounds__(256) void final_kernel(const uint16_t* __restrict__ x1, const uint16_t* __restrict__ x2,
                                                    const uint16_t* __restrict__ x3,
                                                    const uint16_t* __restrict__ Wlb, const float* __restrict__ bl,
                                                    float* __restrict__ out) {
  __shared__ uint16_t ldsA[4 * 64 * 8];    // [chunk][row 0..63][8] = 4KB
  __shared__ uint16_t ldsW[4 * 64 * 8];    // [chunk][wrow 0..63][8] (rows 48..63 dup of 47, never read)
  int t = threadIdx.x;
  int lane = t & 63, wave = t >> 6;
  int n0 = blockIdx.x * 64;
  int l15 = lane & 15, quad = lane >> 4;

  int sc2 = t >> 6, sr = t & 63;           // staging: thread t covers chunk sc2, row sr
  int rowA = n0 + sr; if (rowA >= NN) rowA = NN - 1;
  int rowW = sr < 48 ? sr : 47;

  f32x4 acc[3];
  #pragma unroll
  for (int i = 0; i < 3; ++i) acc[i] = (f32x4){0.f, 0.f, 0.f, 0.f};

  #pragma unroll
  for (int kt = 0; kt < 12; ++kt) {
    const uint16_t* xs = (kt < 4) ? x1 : (kt < 8) ? x2 : x3;
    int klocal = (kt & 3) * 32 + sc2 * 8;
    __builtin_amdgcn_global_load_lds(AS1(xs + (size_t)rowA*HID + klocal), AS3(&ldsA[t * 8]), 16, 0, 0);
    __builtin_amdgcn_global_load_lds(AS1(Wlb + (size_t)rowW*384 + kt*32 + sc2*8), AS3(&ldsW[t * 8]), 16, 0, 0);
    __syncthreads();
    bf16x8 af = *(const bf16x8*)&ldsA[(quad * 64 + wave * 16 + l15) * 8];
    #pragma unroll
    for (int nt = 0; nt < 3; ++nt) {
      bf16x8 wf = *(const bf16x8*)&ldsW[(quad * 64 + nt * 16 + l15) * 8];
      acc[nt] = __builtin_amdgcn_mfma_f32_16x16x32_bf16(af, wf, acc[nt], 0, 0, 0);
    }
    __syncthreads();
  }

  int nb = n0 + wave * 16;
  float bias[3]; bool valid[3];
  #pragma unroll
  for (int nt = 0; nt < 3; ++nt) {
    int c = nt*16 + l15;
    valid[nt] = (c < CLS);
    bias[nt] = valid[nt] ? bl[c] : 0.f;
  }

  #pragma unroll
  for (int i = 0; i < 4; ++i) {
    int r = nb + quad*4 + i;
    float v0 = acc[0][i] + bias[0];
    float v1 = acc[1][i] + bias[1];
    float v2 = valid[2] ? (acc[2][i] + bias[2]) : -INFINITY;
    float m = fmaxf(v0, fmaxf(v1, v2));
    #pragma unroll
    for (int off = 8; off >= 1; off >>= 1) m = fmaxf(m, __shfl_xor(m, off, 64));
    float s = __expf(v0 - m) + __expf(v1 - m) + (valid[2] ? __expf(v2 - m) : 0.f);
    #pragma unroll
    for (int off = 8; off >= 1; off >>= 1) s += __shfl_xor(s, off, 64);
    float lse = m + __logf(s);
    if (r < NN) {
      out[(size_t)r*CLS + l15]      = v0 - lse;
      out[(size_t)r*CLS + 16 + l15] = v1 - lse;
      if (valid[2]) out[(size_t)r*CLS + 32 + l15] = v2 - lse;
    }
  }
}

extern "C" void kernel_launch(void* const* d_in, const int* in_sizes, int n_in,
                              void* d_out, int out_size, void* d_ws, size_t ws_size,
                              hipStream_t stream) {
  (void)in_sizes; (void)n_in; (void)out_size; (void)ws_size;
  const float* x0  = (const float*)d_in[0];
  const int*   ei  = (const int*)d_in[1];
  const float* ew  = (const float*)d_in[2];
  const float* W1r = (const float*)d_in[3];
  const float* W1o = (const float*)d_in[4];
  const float* b1  = (const float*)d_in[5];
  const float* W2r = (const float*)d_in[6];
  const float* W2o = (const float*)d_in[7];
  const float* b2  = (const float*)d_in[8];
  const float* W3r = (const float*)d_in[9];
  const float* W3o = (const float*)d_in[10];
  const float* b3  = (const float*)d_in[11];
  const float* Wl  = (const float*)d_in[12];
  const float* bl  = (const float*)d_in[13];
  const int* src = ei;
  const int* dst = ei + NE;

  char* ws = (char*)d_ws;
  size_t off = 0;
  auto alloc = [&](size_t bytes) -> void* {
    void* p = ws + off;
    off += (bytes + 255) & ~(size_t)255;
    return p;
  };
  uint16_t* x0p = (uint16_t*)alloc((size_t)NN * HID * 2);   // also reused as xb2
  uint16_t* xb1 = (uint16_t*)alloc((size_t)NN * HID * 2);
  uint16_t* xb3 = (uint16_t*)alloc((size_t)NN * HID * 2);
  uint16_t* agg = (uint16_t*)alloc((size_t)NN * HID * 2);
  int2*   erec      = (int2*)alloc((size_t)(NE + 16) * 8);  // +16 zero-weight pad recs
  int2*   ebin      = (int2*)alloc((size_t)NE * 8);         // dead after bucket_csr -> reused as xb1f8
  int*    row_start = (int*)alloc((size_t)(NN + 1) * 4);
  int*    bcnt      = (int*)alloc(NBUK * 4);
  int*    bfill     = (int*)alloc(NBUK * 4);
  int*    bbase     = (int*)alloc((NBUK + 1) * 4);
  uint16_t* B1 = (uint16_t*)alloc(128 * 256 * 2);
  uint16_t* B2 = (uint16_t*)alloc(128 * 256 * 2);
  uint16_t* B3 = (uint16_t*)alloc(128 * 256 * 2);
  uint16_t* Wlb = (uint16_t*)alloc(48 * 384 * 2);
  uint8_t* x0f8  = (uint8_t*)alloc((size_t)NN * 128);
  uint8_t* xb2f8 = (uint8_t*)alloc((size_t)NN * 128);
  uint16_t* xb2 = x0p;                 // alias: x0p dead after layer-1 GEMM
  uint8_t* xb1f8 = (uint8_t*)ebin;     // alias: ebin dead after bucket_csr (NE*8 >= NN*128)

  const int TB = (NE + 8191) / 8192;      // 196 tiles

  hipMemsetAsync(bcnt, 0, NBUK * 4, stream);
  hipMemsetAsync(erec + NE, 0, 16 * sizeof(int2), stream);  // pad: w=0, offset 0
  pack_weights<<<384, 256, 0, stream>>>(W1r, W1o, W2r, W2o, W3r, W3o, B1, B2, B3);
  pack_wl<<<72, 256, 0, stream>>>(Wl, Wlb);
  pad_x0<<<NN / 4, 256, 0, stream>>>(x0, x0p, x0f8);
  bucket_hist<<<TB, 512, 0, stream>>>(dst, bcnt);
  bucket_scan<<<1, 512, 0, stream>>>(bcnt, bfill, bbase);
  binscat<<<TB, 512, 0, stream>>>(src, dst, ew, bfill, ebin);
  bucket_csr<<<NBUK, 256, 0, stream>>>(ebin, bbase, row_start, erec);

  spmm_kernel<<<NN / 8, 256, 0, stream>>>(x0f8, row_start, erec, agg);
  gemm_kernel<<<(NN + 127) / 128, 256, 0, stream>>>(agg, x0p, B1, b1, xb1, xb1f8);
  spmm_kernel<<<NN / 8, 256, 0, stream>>>(xb1f8, row_start, erec, agg);
  gemm_kernel<<<(NN + 127) / 128, 256, 0, stream>>>(agg, xb1, B2, b2, xb2, xb2f8);
  spmm_kernel<<<NN / 8, 256, 0, stream>>>(xb2f8, row_start, erec, agg);
  gemm_kernel<<<(NN + 127) / 128, 256, 0, stream>>>(agg, xb2, B3, b3, xb3, nullptr);

  final_kernel<<<(NN + 63) / 64, 256, 0, stream>>>(xb1, xb2, xb3, Wlb, bl, (float*)d_out);
}